// Round 7
// baseline (11853.395 us; speedup 1.0000x reference)
//
#include <hip/hip_runtime.h>
#include <hip/hip_bf16.h>

// Problem dims
#define B_   64
#define S_   256
#define E_   512
#define H_   1024
#define D_   512
#define C_   2
#define G4   4096   // 4*H
#define NB   256    // blocks in persistent recurrence

typedef __attribute__((ext_vector_type(8))) short short8;   // 8 bf16 (4 VGPRs)
typedef __attribute__((ext_vector_type(4))) float f32x4;

__device__ __forceinline__ float bf2f(unsigned short u) {
    unsigned int x = ((unsigned int)u) << 16;
    return __uint_as_float(x);
}
__device__ __forceinline__ unsigned short f2bf(float f) {
    unsigned int x = __float_as_uint(f);
    unsigned int r = (x + 0x7fffu + ((x >> 16) & 1u)) >> 16;
    return (unsigned short)r;
}

// ---------------------------------------------------------------------------
// Kernel D: detect fp32 (flag=1) vs bf16 (flag=0) float inputs (probe emb).
__global__ void detect_kernel(const unsigned short* __restrict__ emb_u,
                              int* __restrict__ flag)
{
    __shared__ int cnt;
    if (threadIdx.x == 0) cnt = 0;
    __syncthreads();
    int bad = 0;
#pragma unroll
    for (int i = 0; i < 8; ++i) {
        unsigned short u = emb_u[threadIdx.x * 8 + i];
        float a = fabsf(bf2f(u));
        if (!(a < 4.0f)) bad = 1;
        else if (a != 0.0f && a < 1e-20f) bad = 1;
    }
    if (bad) atomicAdd(&cnt, 1);
    __syncthreads();
    if (threadIdx.x == 0) *flag = (cnt > 16) ? 1 : 0;
}

// ---------------------------------------------------------------------------
// Workspace float offsets
#define OFF_WFX   0L          // 2097152  (Wx rows 0..511, fp32 [k][n])
#define OFF_WB    2097152L    // 4194304 floats = 8.4M ushort: MFMA B-frags
                              //   WB[bk][ks][term][lane][8]  (hi=term0, lo=term1)
#define OFF_BIAS  6291456L    // 4096
#define OFF_WD    6295552L    // 524288
#define OFF_DB    6819840L    // 512
#define OFF_WP    6820352L    // 1024
#define OFF_PB    6821376L    // 16 (2 used)
#define OFF_FH    6821392L    // 65536
#define OFF_DEN   6886928L    // 32768
#define OFF_HH    6919696L    // 131072 floats = 4 ushort bufs of 65536:
                              //   hHiA, hLoA, hHiB, hLoB   ([b][k] bf16)
#define OFF_BAR   7050768L    // 512 uints: subs@0..224(стride32), master@256, gen@288, flag@400
#define OFF_XPROJ 7051280L    // 67108864

// Kernel P: convert/relayout weights (incl. bf16 hi/lo MFMA-frag order),
// zero fhT, h t=0 buffers, barrier counters.
// Items: Wfx 2097152 | WBpairs 4194304 | bias 4096 | Wd 524288 | db 512 |
//        Wp 1024 | pb 2 | fhT 65536 | hA-zero 65536 (uints) | bar 320
#define PREP_TOTAL 6952770
__global__ void prep_kernel(const void* __restrict__ lk,
                            const void* __restrict__ lb,
                            const void* __restrict__ dw,
                            const void* __restrict__ dbm,
                            const void* __restrict__ pw,
                            const void* __restrict__ pbm,
                            const int* __restrict__ flag,
                            float* __restrict__ w)
{
    const bool f32 = (*flag != 0);
    long i = (long)blockIdx.x * 256 + threadIdx.x;
    if (i >= PREP_TOTAL) return;
#define CV(p, j) (f32 ? ((const float*)(p))[j] : bf2f(((const unsigned short*)(p))[j]))
    if (i < 2097152) { w[OFF_WFX + i] = CV(lk, i); return; }  i -= 2097152;
    if (i < 4194304) {
        // B-frag relayout: block bk owns cols c=g*4+jj (n = g*1024 + bk*4+jj).
        // lane l holds B[k = ks*32 + (l>>4)*8 + j][c = l&15], j=0..7.
        int j  = (int)(i & 7);
        int l  = (int)((i >> 3) & 63);
        int ks = (int)((i >> 9) & 31);
        int bk = (int)(i >> 14);
        int c  = l & 15, q = l >> 4;
        int k  = ks * 32 + q * 8 + j;
        int g  = c >> 2, jj = c & 3;
        long src = (long)(512 + k) * G4 + g * H_ + bk * 4 + jj;
        float v = CV(lk, src);
        unsigned short hi = f2bf(v);
        unsigned short lo = f2bf(v - bf2f(hi));
        unsigned short* WBu = (unsigned short*)(w + OFF_WB);
        long base = ((long)(bk * 32 + ks) * 2) * 512 + l * 8 + j;
        WBu[base]       = hi;   // term 0
        WBu[base + 512] = lo;   // term 1
        return;
    }  i -= 4194304;
    if (i < 4096)    { w[OFF_BIAS + i] = CV(lb, i);  return; }  i -= 4096;
    if (i < 524288)  { w[OFF_WD + i]   = CV(dw, i);  return; }  i -= 524288;
    if (i < 512)     { w[OFF_DB + i]   = CV(dbm, i); return; }  i -= 512;
    if (i < 1024)    { w[OFF_WP + i]   = CV(pw, i);  return; }  i -= 1024;
    if (i < 2)       { w[OFF_PB + i]   = CV(pbm, i); return; }  i -= 2;
    if (i < 65536)   { w[OFF_FH + i] = 0.f; return; }  i -= 65536;
    if (i < 65536)   { ((unsigned int*)(w + OFF_HH))[i] = 0u; return; }  i -= 65536;
    if (i < 320)     { ((unsigned int*)(w + OFF_BAR))[i] = 0u; return; }
#undef CV
}

// ---------------------------------------------------------------------------
// Kernel A: xprojT[t][n][b] = sum_e emb[X[b,t]][e] * Wfx[e][n] + bias[n]
__global__ __launch_bounds__(256) void xproj_kernel(
    const int* __restrict__ X,
    const void* __restrict__ emb,
    const int* __restrict__ flag,
    const float* __restrict__ Wfx,
    const float* __restrict__ biasf,
    float* __restrict__ xprojT)
{
    const int t    = blockIdx.y;
    const int cb   = blockIdx.x;
    const int tid  = threadIdx.x;
    const int lane = tid & 63;
    const int wv   = __builtin_amdgcn_readfirstlane(tid >> 6);
    const bool f32 = (*flag != 0);

    __shared__ float embT[128 * 64];
    __shared__ int   rowid[64];

    if (tid < 64) rowid[tid] = X[tid * S_ + t];
    __syncthreads();

    const int n0 = cb * 64 + wv * 16;
    float acc[16];
#pragma unroll
    for (int c = 0; c < 16; ++c) acc[c] = biasf[n0 + c];

    const long myrow = (long)rowid[lane] * E_;

    for (int kc = 0; kc < 4; ++kc) {
        const int k0 = kc * 128;
        if (f32) {
            const float4* src = (const float4*)((const float*)emb + myrow + k0 + wv * 32);
#pragma unroll
            for (int u = 0; u < 8; ++u) {
                float4 v = src[u];
                int kl = wv * 32 + u * 4;
                embT[(kl + 0) * 64 + lane] = v.x;
                embT[(kl + 1) * 64 + lane] = v.y;
                embT[(kl + 2) * 64 + lane] = v.z;
                embT[(kl + 3) * 64 + lane] = v.w;
            }
        } else {
            const uint4* src = (const uint4*)((const unsigned short*)emb + myrow + k0 + wv * 32);
#pragma unroll
            for (int u = 0; u < 4; ++u) {
                uint4 v = src[u];
                int kl = wv * 32 + u * 8;
                embT[(kl + 0) * 64 + lane] = bf2f((unsigned short)(v.x & 0xffff));
                embT[(kl + 1) * 64 + lane] = bf2f((unsigned short)(v.x >> 16));
                embT[(kl + 2) * 64 + lane] = bf2f((unsigned short)(v.y & 0xffff));
                embT[(kl + 3) * 64 + lane] = bf2f((unsigned short)(v.y >> 16));
                embT[(kl + 4) * 64 + lane] = bf2f((unsigned short)(v.z & 0xffff));
                embT[(kl + 5) * 64 + lane] = bf2f((unsigned short)(v.z >> 16));
                embT[(kl + 6) * 64 + lane] = bf2f((unsigned short)(v.w & 0xffff));
                embT[(kl + 7) * 64 + lane] = bf2f((unsigned short)(v.w >> 16));
            }
        }
        __syncthreads();

        const float* wbase = Wfx + (long)k0 * G4 + n0;
#pragma unroll 2
        for (int k = 0; k < 128; ++k) {
            float hv = embT[k * 64 + lane];
            const float* wr = wbase + (long)k * G4;
#pragma unroll
            for (int c = 0; c < 16; ++c) acc[c] += wr[c] * hv;
        }
        __syncthreads();
    }

    float* dst = xprojT + ((long)t * G4 + n0) * 64 + lane;
#pragma unroll
    for (int c = 0; c < 16; ++c) dst[c * 64] = acc[c];
}

// ---------------------------------------------------------------------------
// Hierarchical monotonic grid barrier (8 sub-counters + master, no resets).
__device__ __forceinline__ void grid_barrier(unsigned int* bar, int t)
{
    __syncthreads();
    if (threadIdx.x == 0) {
        __threadfence();   // release h/c stores (agent scope)
        unsigned int* sub    = bar + ((blockIdx.x & 7) << 5);
        unsigned int* master = bar + 256;
        unsigned int* gen    = bar + 288;
        unsigned int a = __hip_atomic_fetch_add(sub, 1u, __ATOMIC_ACQ_REL, __HIP_MEMORY_SCOPE_AGENT);
        if (a == (unsigned)(t * 32 + 31)) {
            unsigned int m = __hip_atomic_fetch_add(master, 1u, __ATOMIC_ACQ_REL, __HIP_MEMORY_SCOPE_AGENT);
            if (m == (unsigned)(t * 8 + 7))
                __hip_atomic_store(gen, (unsigned)(t + 1), __ATOMIC_RELEASE, __HIP_MEMORY_SCOPE_AGENT);
        }
        while (__hip_atomic_load(gen, __ATOMIC_ACQUIRE, __HIP_MEMORY_SCOPE_AGENT) <= (unsigned)t) {
            __builtin_amdgcn_s_sleep(1);
        }
        __threadfence();   // acquire: fresh h reads next step
    }
    __syncthreads();
}

// ---------------------------------------------------------------------------
// Persistent MFMA LSTM recurrence. 256 blocks x 256 thr (4 waves).
// Block bk owns h-dims j0=bk*4..+3 -> 16 gate cols c=g*4+jj.
// Weights: bf16 hi/lo B-frags, LDS-resident (staged once, 64 KB).
// h: bf16 hi/lo [b][k] in global, split written by pointwise phase.
// Wave wv computes M-tile rows [wv*16, wv*16+16) via 3-product split MFMA.
__global__ __launch_bounds__(256) void lstm_persistent(
    unsigned short* __restrict__ hU,     // hHiA | hLoA | hHiB | hLoB (65536 each)
    float* __restrict__ fhT,
    const unsigned short* __restrict__ WBg,
    const float* __restrict__ xprojT,
    const int* __restrict__ seqlen, unsigned int* __restrict__ bar)
{
    const int tid  = threadIdx.x;
    const int lane = tid & 63;
    const int wv   = __builtin_amdgcn_readfirstlane(tid >> 6);  // 0..3
    const int bk   = blockIdx.x;

    __shared__ unsigned short WBl[32768];   // 64 KB B-frags [ks][term][lane][8]
    __shared__ float gates[64 * 17];        // [m=b][c] +pad
    __shared__ float cTl[256];              // [jj][b] cell state, LDS-resident

    // stage weight frags (once) + init c
    {
        const uint4* src = (const uint4*)(WBg + (long)bk * 32768);
        uint4* dst = (uint4*)WBl;
#pragma unroll
        for (int u = 0; u < 16; ++u) dst[tid + u * 256] = src[tid + u * 256];
        cTl[tid] = 0.f;
    }
    __syncthreads();

    const int myseq = seqlen[lane];
    const int q = lane >> 4, c = lane & 15;

    unsigned short* hHiA = hU;
    unsigned short* hLoA = hU + 65536;
    unsigned short* hHiB = hU + 131072;
    unsigned short* hLoB = hU + 196608;

    unsigned short *curHi = hHiA, *curLo = hLoA, *nxtHi = hHiB, *nxtLo = hLoB;

    for (int t = 0; t < S_; ++t) {
        // prefetch xproj for pointwise (thread = (jj=wv, b=lane))
        const long xb = (long)t * G4 + bk * 4 + wv;
        const float xq0 = xprojT[(xb + 0 * H_) * 64 + lane];
        const float xq1 = xprojT[(xb + 1 * H_) * 64 + lane];
        const float xq2 = xprojT[(xb + 2 * H_) * 64 + lane];
        const float xq3 = xprojT[(xb + 3 * H_) * 64 + lane];

        // A-frag row base: rows m = wv*16 + (lane&15), k-offset (lane>>4)*8
        const unsigned short* hiRow = curHi + (wv * 16 + c) * H_ + q * 8;
        const unsigned short* loRow = curLo + (wv * 16 + c) * H_ + q * 8;

        f32x4 acc0 = {0.f, 0.f, 0.f, 0.f};
        f32x4 acc1 = {0.f, 0.f, 0.f, 0.f};
        f32x4 acc2 = {0.f, 0.f, 0.f, 0.f};

#pragma unroll 8
        for (int ks = 0; ks < 32; ++ks) {
            short8 ahi = *(const short8*)(hiRow + ks * 32);
            short8 alo = *(const short8*)(loRow + ks * 32);
            short8 bhi = *(const short8*)(&WBl[(ks * 2 + 0) * 512 + (lane << 3)]);
            short8 blo = *(const short8*)(&WBl[(ks * 2 + 1) * 512 + (lane << 3)]);
            acc0 = __builtin_amdgcn_mfma_f32_16x16x32_bf16(ahi, bhi, acc0, 0, 0, 0);
            acc1 = __builtin_amdgcn_mfma_f32_16x16x32_bf16(ahi, blo, acc1, 0, 0, 0);
            acc2 = __builtin_amdgcn_mfma_f32_16x16x32_bf16(alo, bhi, acc2, 0, 0, 0);
        }

        // C tile -> LDS: lane (q,c), reg r holds C[m = wv*16 + q*4 + r][c]
#pragma unroll
        for (int r = 0; r < 4; ++r)
            gates[(wv * 16 + q * 4 + r) * 17 + c] = acc0[r] + acc1[r] + acc2[r];
        __syncthreads();

        // pointwise: thread (jj=wv, b=lane); gate order i,j,f,o
        {
            const int jj = wv, b = lane;
            const float gi = gates[b * 17 +  0 + jj] + xq0;
            const float gj = gates[b * 17 +  4 + jj] + xq1;
            const float gf = gates[b * 17 +  8 + jj] + xq2;
            const float go = gates[b * 17 + 12 + jj] + xq3;

            const float c_old = cTl[jj * 64 + b];
            const float fgate = 1.f / (1.f + expf(-(gf + 1.0f)));  // forget bias
            const float igate = 1.f / (1.f + expf(-gi));
            const float ogate = 1.f / (1.f + expf(-go));
            const float cnew  = c_old * fgate + igate * tanhf(gj);
            const float hnew  = tanhf(cnew) * ogate;
            cTl[jj * 64 + b] = cnew;

            const int j = bk * 4 + jj;
            const unsigned short hi = f2bf(hnew);
            const unsigned short lo = f2bf(hnew - bf2f(hi));
            nxtHi[b * H_ + j] = hi;
            nxtLo[b * H_ + j] = lo;
            if (t == myseq - 1) fhT[j * 64 + b] = hnew;
        }

        grid_barrier(bar, t);

        unsigned short* s;
        s = curHi; curHi = nxtHi; nxtHi = s;
        s = curLo; curLo = nxtLo; nxtLo = s;
    }
}

// ---------------------------------------------------------------------------
// Kernel C1: denseT[d][b] = relu(fh[b] . dense_w[:,d] + db[d])
__global__ __launch_bounds__(256) void dense_kernel(
    const float* __restrict__ fhT, const float* __restrict__ Wdf,
    const float* __restrict__ dbf, float* __restrict__ denseT)
{
    const int tid  = threadIdx.x;
    const int lane = tid & 63;
    const int wv   = __builtin_amdgcn_readfirstlane(tid >> 6);
    const int d0   = blockIdx.x * 16 + wv * 4;

    float acc[4] = {0.f, 0.f, 0.f, 0.f};
#pragma unroll 4
    for (int k = 0; k < H_; ++k) {
        float v = fhT[k * 64 + lane];
        const float* wr = Wdf + (long)k * D_ + d0;
        acc[0] += wr[0] * v;
        acc[1] += wr[1] * v;
        acc[2] += wr[2] * v;
        acc[3] += wr[3] * v;
    }
#pragma unroll
    for (int c = 0; c < 4; ++c) {
        float z = acc[c] + dbf[d0 + c];
        z = z > 0.f ? z : 0.f;
        denseT[(d0 + c) * 64 + lane] = z;
    }
}

// Kernel C2: logits; output dtype follows detected input dtype.
__global__ void logits_kernel(const float* __restrict__ denseT,
                              const float* __restrict__ Wpf,
                              const float* __restrict__ pbf,
                              const int* __restrict__ flag,
                              void* __restrict__ out)
{
    const int tid  = threadIdx.x;      // 128 threads: 2 waves
    const int lane = tid & 63;
    const int c    = __builtin_amdgcn_readfirstlane(tid >> 6);
    float acc = 0.f;
#pragma unroll 4
    for (int k = 0; k < D_; ++k)
        acc += denseT[k * 64 + lane] * Wpf[k * C_ + c];
    const float r = acc + pbf[c];
    if (*flag != 0) ((float*)out)[lane * C_ + c] = r;
    else            ((unsigned short*)out)[lane * C_ + c] = f2bf(r);
}

// ---------------------------------------------------------------------------
extern "C" void kernel_launch(void* const* d_in, const int* in_sizes, int n_in,
                              void* d_out, int out_size, void* d_ws, size_t ws_size,
                              hipStream_t stream)
{
    // Map inputs by unique flat element counts; fall back to positional.
    const int want[9] = {16384, 64, 25600000, 6291456, 4096, 524288, 512, 1024, 2};
    const void* p[9];
    for (int i = 0; i < 9; ++i) p[i] = d_in[i];
    if (n_in == 9) {
        bool ok = true;
        const void* q[9];
        for (int i = 0; i < 9; ++i) {
            int found = -1;
            for (int j = 0; j < 9; ++j) if (in_sizes[j] == want[i]) { found = j; break; }
            if (found < 0) { ok = false; break; }
            q[i] = d_in[found];
        }
        if (ok) for (int i = 0; i < 9; ++i) p[i] = q[i];
    }
    const int*  X      = (const int*)p[0];
    const int*  seqlen = (const int*)p[1];
    const void* emb    = p[2];
    const void* lk     = p[3];
    const void* lb     = p[4];
    const void* dw     = p[5];
    const void* dbm    = p[6];
    const void* pw     = p[7];
    const void* pbm    = p[8];

    float* w = (float*)d_ws;
    unsigned int* bar  = (unsigned int*)(w + OFF_BAR);
    int*          flag = (int*)bar + 400;   // outside zeroed [0,320) range

    detect_kernel<<<1, 256, 0, stream>>>((const unsigned short*)emb, flag);

    prep_kernel<<<(PREP_TOTAL + 255) / 256, 256, 0, stream>>>(
        lk, lb, dw, dbm, pw, pbm, flag, w);

    xproj_kernel<<<dim3(64, 256), 256, 0, stream>>>(X, emb, flag,
                                                    w + OFF_WFX, w + OFF_BIAS,
                                                    w + OFF_XPROJ);

    lstm_persistent<<<NB, 256, 0, stream>>>((unsigned short*)(w + OFF_HH),
                                            w + OFF_FH,
                                            (const unsigned short*)(w + OFF_WB),
                                            w + OFF_XPROJ,
                                            seqlen, bar);

    dense_kernel<<<32, 256, 0, stream>>>(w + OFF_FH, w + OFF_WD,
                                         w + OFF_DB, w + OFF_DEN);
    logits_kernel<<<1, 128, 0, stream>>>(w + OFF_DEN, w + OFF_WP,
                                         w + OFF_PB, flag, d_out);
}

// Round 8
// 11247.343 us; speedup vs baseline: 1.0539x; 1.0539x over previous
//
#include <hip/hip_runtime.h>
#include <hip/hip_bf16.h>

// Problem dims
#define B_   64
#define S_   256
#define E_   512
#define H_   1024
#define D_   512
#define C_   2
#define G4   4096   // 4*H
#define NB   256    // blocks in persistent recurrence (== block size for flag poll)

typedef __attribute__((ext_vector_type(8))) short short8;   // 8 bf16 (4 VGPRs)
typedef __attribute__((ext_vector_type(4))) float f32x4;

__device__ __forceinline__ float bf2f(unsigned short u) {
    unsigned int x = ((unsigned int)u) << 16;
    return __uint_as_float(x);
}
__device__ __forceinline__ unsigned short f2bf(float f) {
    unsigned int x = __float_as_uint(f);
    unsigned int r = (x + 0x7fffu + ((x >> 16) & 1u)) >> 16;
    return (unsigned short)r;
}

// ---------------------------------------------------------------------------
// Kernel D: detect fp32 (flag=1) vs bf16 (flag=0) float inputs (probe emb).
__global__ void detect_kernel(const unsigned short* __restrict__ emb_u,
                              int* __restrict__ flag)
{
    __shared__ int cnt;
    if (threadIdx.x == 0) cnt = 0;
    __syncthreads();
    int bad = 0;
#pragma unroll
    for (int i = 0; i < 8; ++i) {
        unsigned short u = emb_u[threadIdx.x * 8 + i];
        float a = fabsf(bf2f(u));
        if (!(a < 4.0f)) bad = 1;
        else if (a != 0.0f && a < 1e-20f) bad = 1;
    }
    if (bad) atomicAdd(&cnt, 1);
    __syncthreads();
    if (threadIdx.x == 0) *flag = (cnt > 16) ? 1 : 0;
}

// ---------------------------------------------------------------------------
// Workspace float offsets
#define OFF_WFX   0L          // 2097152  (Wx rows 0..511, fp32 [k][n])
#define OFF_WB    2097152L    // 4194304 floats = 8.4M ushort: MFMA B-frags
                              //   WB[bk][ks][term][lane][8]  (hi=term0, lo=term1)
#define OFF_BIAS  6291456L    // 4096
#define OFF_WD    6295552L    // 524288
#define OFF_DB    6819840L    // 512
#define OFF_WP    6820352L    // 1024
#define OFF_PB    6821376L    // 16 (2 used)
#define OFF_FH    6821392L    // 65536
#define OFF_DEN   6886928L    // 32768
#define OFF_HH    6919696L    // 131072 floats = 4 ushort bufs of 65536:
                              //   A-frag-order h: hiA, loA, hiB, loB
#define OFF_BAR   7050768L    // 512 uints: done[256]@0, flag@400
#define OFF_XPROJ 7051280L    // 67108864

// Kernel P: convert/relayout weights (bf16 hi/lo MFMA B-frag order),
// zero fhT, t=0 h buffers (hiA, loA), done[] flags.
// Items: Wfx 2097152 | WBpairs 4194304 | bias 4096 | Wd 524288 | db 512 |
//        Wp 1024 | pb 2 | fhT 65536 | h-zero 65536 uints | bar 320
#define PREP_TOTAL 6952770
__global__ void prep_kernel(const void* __restrict__ lk,
                            const void* __restrict__ lb,
                            const void* __restrict__ dw,
                            const void* __restrict__ dbm,
                            const void* __restrict__ pw,
                            const void* __restrict__ pbm,
                            const int* __restrict__ flag,
                            float* __restrict__ w)
{
    const bool f32 = (*flag != 0);
    long i = (long)blockIdx.x * 256 + threadIdx.x;
    if (i >= PREP_TOTAL) return;
#define CV(p, j) (f32 ? ((const float*)(p))[j] : bf2f(((const unsigned short*)(p))[j]))
    if (i < 2097152) { w[OFF_WFX + i] = CV(lk, i); return; }  i -= 2097152;
    if (i < 4194304) {
        // B-frag relayout: block bk owns cols c=g*4+jj (n = g*1024 + bk*4+jj).
        // lane l holds B[k = ks*32 + (l>>4)*8 + j][c = l&15], j=0..7.
        int j  = (int)(i & 7);
        int l  = (int)((i >> 3) & 63);
        int ks = (int)((i >> 9) & 31);
        int bk = (int)(i >> 14);
        int c  = l & 15, q = l >> 4;
        int k  = ks * 32 + q * 8 + j;
        int g  = c >> 2, jj = c & 3;
        long src = (long)(512 + k) * G4 + g * H_ + bk * 4 + jj;
        float v = CV(lk, src);
        unsigned short hi = f2bf(v);
        unsigned short lo = f2bf(v - bf2f(hi));
        unsigned short* WBu = (unsigned short*)(w + OFF_WB);
        long base = ((long)(bk * 32 + ks) * 2) * 512 + l * 8 + j;
        WBu[base]       = hi;   // term 0
        WBu[base + 512] = lo;   // term 1
        return;
    }  i -= 4194304;
    if (i < 4096)    { w[OFF_BIAS + i] = CV(lb, i);  return; }  i -= 4096;
    if (i < 524288)  { w[OFF_WD + i]   = CV(dw, i);  return; }  i -= 524288;
    if (i < 512)     { w[OFF_DB + i]   = CV(dbm, i); return; }  i -= 512;
    if (i < 1024)    { w[OFF_WP + i]   = CV(pw, i);  return; }  i -= 1024;
    if (i < 2)       { w[OFF_PB + i]   = CV(pbm, i); return; }  i -= 2;
    if (i < 65536)   { w[OFF_FH + i] = 0.f; return; }  i -= 65536;
    if (i < 65536)   { ((unsigned int*)(w + OFF_HH))[i] = 0u; return; }  i -= 65536;
    if (i < 320)     { ((unsigned int*)(w + OFF_BAR))[i] = 0u; return; }
#undef CV
}

// ---------------------------------------------------------------------------
// Kernel A: xprojT[t][n][b] = sum_e emb[X[b,t]][e] * Wfx[e][n] + bias[n]
__global__ __launch_bounds__(256) void xproj_kernel(
    const int* __restrict__ X,
    const void* __restrict__ emb,
    const int* __restrict__ flag,
    const float* __restrict__ Wfx,
    const float* __restrict__ biasf,
    float* __restrict__ xprojT)
{
    const int t    = blockIdx.y;
    const int cb   = blockIdx.x;
    const int tid  = threadIdx.x;
    const int lane = tid & 63;
    const int wv   = __builtin_amdgcn_readfirstlane(tid >> 6);
    const bool f32 = (*flag != 0);

    __shared__ float embT[128 * 64];
    __shared__ int   rowid[64];

    if (tid < 64) rowid[tid] = X[tid * S_ + t];
    __syncthreads();

    const int n0 = cb * 64 + wv * 16;
    float acc[16];
#pragma unroll
    for (int c = 0; c < 16; ++c) acc[c] = biasf[n0 + c];

    const long myrow = (long)rowid[lane] * E_;

    for (int kc = 0; kc < 4; ++kc) {
        const int k0 = kc * 128;
        if (f32) {
            const float4* src = (const float4*)((const float*)emb + myrow + k0 + wv * 32);
#pragma unroll
            for (int u = 0; u < 8; ++u) {
                float4 v = src[u];
                int kl = wv * 32 + u * 4;
                embT[(kl + 0) * 64 + lane] = v.x;
                embT[(kl + 1) * 64 + lane] = v.y;
                embT[(kl + 2) * 64 + lane] = v.z;
                embT[(kl + 3) * 64 + lane] = v.w;
            }
        } else {
            const uint4* src = (const uint4*)((const unsigned short*)emb + myrow + k0 + wv * 32);
#pragma unroll
            for (int u = 0; u < 4; ++u) {
                uint4 v = src[u];
                int kl = wv * 32 + u * 8;
                embT[(kl + 0) * 64 + lane] = bf2f((unsigned short)(v.x & 0xffff));
                embT[(kl + 1) * 64 + lane] = bf2f((unsigned short)(v.x >> 16));
                embT[(kl + 2) * 64 + lane] = bf2f((unsigned short)(v.y & 0xffff));
                embT[(kl + 3) * 64 + lane] = bf2f((unsigned short)(v.y >> 16));
                embT[(kl + 4) * 64 + lane] = bf2f((unsigned short)(v.z & 0xffff));
                embT[(kl + 5) * 64 + lane] = bf2f((unsigned short)(v.z >> 16));
                embT[(kl + 6) * 64 + lane] = bf2f((unsigned short)(v.w & 0xffff));
                embT[(kl + 7) * 64 + lane] = bf2f((unsigned short)(v.w >> 16));
            }
        }
        __syncthreads();

        const float* wbase = Wfx + (long)k0 * G4 + n0;
#pragma unroll 2
        for (int k = 0; k < 128; ++k) {
            float hv = embT[k * 64 + lane];
            const float* wr = wbase + (long)k * G4;
#pragma unroll
            for (int c = 0; c < 16; ++c) acc[c] += wr[c] * hv;
        }
        __syncthreads();
    }

    float* dst = xprojT + ((long)t * G4 + n0) * 64 + lane;
#pragma unroll
    for (int c = 0; c < 16; ++c) dst[c * 64] = acc[c];
}

// ---------------------------------------------------------------------------
// Flag-array grid barrier: each block stores its own monotonic flag (one
// release store, no RMW), then 256 threads poll all 256 flags in parallel.
// Safe with double-buffered h: write-own-then-poll bounds skew to <=1 step.
__device__ __forceinline__ void grid_barrier(unsigned int* done, int t)
{
    __syncthreads();
    if (threadIdx.x == 0) {
        __threadfence();   // make this block's h/flag-ordered stores visible
        __hip_atomic_store(&done[blockIdx.x], (unsigned)(t + 1),
                           __ATOMIC_RELEASE, __HIP_MEMORY_SCOPE_AGENT);
    }
    const unsigned tgt = (unsigned)(t + 1);
    while (!__syncthreads_and(
        (int)(__hip_atomic_load(&done[threadIdx.x], __ATOMIC_RELAXED,
                                __HIP_MEMORY_SCOPE_AGENT) >= tgt))) {
        __builtin_amdgcn_s_sleep(1);
    }
    __threadfence();       // acquire: fresh h reads next step
    __syncthreads();
}

// ---------------------------------------------------------------------------
// Persistent MFMA LSTM recurrence. 256 blocks x 256 thr (4 waves).
// Block bk owns h-dims j0=bk*4..+3 -> 16 gate cols c=g*4+jj.
// Weights: bf16 hi/lo B-frags, LDS-resident (staged once, 64 KB).
// h: bf16 hi/lo in global, stored in A-FRAGMENT ORDER:
//   hfrag[ks][mt][q][c][j8]  (wave wv reads ((ks*4+wv)*64+lane)*8 -> 1KB
//   contiguous per wave load, perfectly coalesced).
__global__ __launch_bounds__(256) void lstm_persistent(
    unsigned short* __restrict__ hU,     // hiA | loA | hiB | loB (65536 each)
    float* __restrict__ fhT,
    const unsigned short* __restrict__ WBg,
    const float* __restrict__ xprojT,
    const int* __restrict__ seqlen, unsigned int* __restrict__ done)
{
    const int tid  = threadIdx.x;
    const int lane = tid & 63;
    const int wv   = __builtin_amdgcn_readfirstlane(tid >> 6);  // 0..3
    const int bk   = blockIdx.x;

    __shared__ unsigned short WBl[32768];   // 64 KB B-frags [ks][term][lane][8]
    __shared__ float gates[64 * 17];        // [m=b][c] +pad
    __shared__ float cTl[256];              // [jj][b] cell state, LDS-resident

    // stage weight frags (once) + init c
    {
        const uint4* src = (const uint4*)(WBg + (long)bk * 32768);
        uint4* dst = (uint4*)WBl;
#pragma unroll
        for (int u = 0; u < 16; ++u) dst[tid + u * 256] = src[tid + u * 256];
        cTl[tid] = 0.f;
    }
    __syncthreads();

    const int myseq = seqlen[lane];
    const int q = lane >> 4, c = lane & 15;

    unsigned short* hiA = hU;
    unsigned short* loA = hU + 65536;
    unsigned short* hiB = hU + 131072;
    unsigned short* loB = hU + 196608;

    unsigned short *curHi = hiA, *curLo = loA, *nxtHi = hiB, *nxtLo = loB;

    // pointwise h-write target (A-frag order), this thread's (j, b):
    //   j = bk*4 + wv, b = lane
    const int jw  = bk * 4 + wv;
    const int wks = jw >> 5, wq = (jw >> 3) & 3, wj8 = jw & 7;
    const long aidx = ((((long)wks * 4 + q * 0 + (lane >> 4)) * 4 + wq) * 16
                       + (lane & 15)) * 8 + wj8;   // mt = lane>>4, cc = lane&15

    for (int t = 0; t < S_; ++t) {
        // prefetch xproj for pointwise (thread = (jj=wv, b=lane))
        const long xb = (long)t * G4 + bk * 4 + wv;
        const float xq0 = xprojT[(xb + 0 * H_) * 64 + lane];
        const float xq1 = xprojT[(xb + 1 * H_) * 64 + lane];
        const float xq2 = xprojT[(xb + 2 * H_) * 64 + lane];
        const float xq3 = xprojT[(xb + 3 * H_) * 64 + lane];

        // A-frag loads: wave wv's tile, contiguous 1KB per load
        const unsigned short* hiP = curHi + ((long)wv * 64 + lane) * 8;
        const unsigned short* loP = curLo + ((long)wv * 64 + lane) * 8;

        f32x4 acc0 = {0.f, 0.f, 0.f, 0.f};
        f32x4 acc1 = {0.f, 0.f, 0.f, 0.f};
        f32x4 acc2 = {0.f, 0.f, 0.f, 0.f};

#pragma unroll 8
        for (int ks = 0; ks < 32; ++ks) {
            short8 ahi = *(const short8*)(hiP + ks * 2048);
            short8 alo = *(const short8*)(loP + ks * 2048);
            short8 bhi = *(const short8*)(&WBl[(ks * 2 + 0) * 512 + (lane << 3)]);
            short8 blo = *(const short8*)(&WBl[(ks * 2 + 1) * 512 + (lane << 3)]);
            acc0 = __builtin_amdgcn_mfma_f32_16x16x32_bf16(ahi, bhi, acc0, 0, 0, 0);
            acc1 = __builtin_amdgcn_mfma_f32_16x16x32_bf16(ahi, blo, acc1, 0, 0, 0);
            acc2 = __builtin_amdgcn_mfma_f32_16x16x32_bf16(alo, bhi, acc2, 0, 0, 0);
        }

        // C tile -> LDS: lane (q,c), reg r holds C[m = wv*16 + q*4 + r][c]
#pragma unroll
        for (int r = 0; r < 4; ++r)
            gates[(wv * 16 + q * 4 + r) * 17 + c] = acc0[r] + acc1[r] + acc2[r];
        __syncthreads();

        // pointwise: thread (jj=wv, b=lane); gate order i,j,f,o
        {
            const int jj = wv, b = lane;
            const float gi = gates[b * 17 +  0 + jj] + xq0;
            const float gj = gates[b * 17 +  4 + jj] + xq1;
            const float gf = gates[b * 17 +  8 + jj] + xq2;
            const float go = gates[b * 17 + 12 + jj] + xq3;

            const float c_old = cTl[jj * 64 + b];
            const float fgate = 1.f / (1.f + expf(-(gf + 1.0f)));  // forget bias
            const float igate = 1.f / (1.f + expf(-gi));
            const float ogate = 1.f / (1.f + expf(-go));
            const float cnew  = c_old * fgate + igate * tanhf(gj);
            const float hnew  = tanhf(cnew) * ogate;
            cTl[jj * 64 + b] = cnew;

            const unsigned short hi = f2bf(hnew);
            const unsigned short lo = f2bf(hnew - bf2f(hi));
            nxtHi[aidx] = hi;
            nxtLo[aidx] = lo;
            if (t == myseq - 1) fhT[(bk * 4 + jj) * 64 + b] = hnew;
        }

        grid_barrier(done, t);

        unsigned short* s;
        s = curHi; curHi = nxtHi; nxtHi = s;
        s = curLo; curLo = nxtLo; nxtLo = s;
    }
}

// ---------------------------------------------------------------------------
// Kernel C1: denseT[d][b] = relu(fh[b] . dense_w[:,d] + db[d])
__global__ __launch_bounds__(256) void dense_kernel(
    const float* __restrict__ fhT, const float* __restrict__ Wdf,
    const float* __restrict__ dbf, float* __restrict__ denseT)
{
    const int tid  = threadIdx.x;
    const int lane = tid & 63;
    const int wv   = __builtin_amdgcn_readfirstlane(tid >> 6);
    const int d0   = blockIdx.x * 16 + wv * 4;

    float acc[4] = {0.f, 0.f, 0.f, 0.f};
#pragma unroll 4
    for (int k = 0; k < H_; ++k) {
        float v = fhT[k * 64 + lane];
        const float* wr = Wdf + (long)k * D_ + d0;
        acc[0] += wr[0] * v;
        acc[1] += wr[1] * v;
        acc[2] += wr[2] * v;
        acc[3] += wr[3] * v;
    }
#pragma unroll
    for (int c = 0; c < 4; ++c) {
        float z = acc[c] + dbf[d0 + c];
        z = z > 0.f ? z : 0.f;
        denseT[(d0 + c) * 64 + lane] = z;
    }
}

// Kernel C2: logits; output dtype follows detected input dtype.
__global__ void logits_kernel(const float* __restrict__ denseT,
                              const float* __restrict__ Wpf,
                              const float* __restrict__ pbf,
                              const int* __restrict__ flag,
                              void* __restrict__ out)
{
    const int tid  = threadIdx.x;      // 128 threads: 2 waves
    const int lane = tid & 63;
    const int c    = __builtin_amdgcn_readfirstlane(tid >> 6);
    float acc = 0.f;
#pragma unroll 4
    for (int k = 0; k < D_; ++k)
        acc += denseT[k * 64 + lane] * Wpf[k * C_ + c];
    const float r = acc + pbf[c];
    if (*flag != 0) ((float*)out)[lane * C_ + c] = r;
    else            ((unsigned short*)out)[lane * C_ + c] = f2bf(r);
}

// ---------------------------------------------------------------------------
extern "C" void kernel_launch(void* const* d_in, const int* in_sizes, int n_in,
                              void* d_out, int out_size, void* d_ws, size_t ws_size,
                              hipStream_t stream)
{
    // Map inputs by unique flat element counts; fall back to positional.
    const int want[9] = {16384, 64, 25600000, 6291456, 4096, 524288, 512, 1024, 2};
    const void* p[9];
    for (int i = 0; i < 9; ++i) p[i] = d_in[i];
    if (n_in == 9) {
        bool ok = true;
        const void* q[9];
        for (int i = 0; i < 9; ++i) {
            int found = -1;
            for (int j = 0; j < 9; ++j) if (in_sizes[j] == want[i]) { found = j; break; }
            if (found < 0) { ok = false; break; }
            q[i] = d_in[found];
        }
        if (ok) for (int i = 0; i < 9; ++i) p[i] = q[i];
    }
    const int*  X      = (const int*)p[0];
    const int*  seqlen = (const int*)p[1];
    const void* emb    = p[2];
    const void* lk     = p[3];
    const void* lb     = p[4];
    const void* dw     = p[5];
    const void* dbm    = p[6];
    const void* pw     = p[7];
    const void* pbm    = p[8];

    float* w = (float*)d_ws;
    unsigned int* done = (unsigned int*)(w + OFF_BAR);
    int*          flag = (int*)done + 400;   // outside zeroed [0,320) range

    detect_kernel<<<1, 256, 0, stream>>>((const unsigned short*)emb, flag);

    prep_kernel<<<(PREP_TOTAL + 255) / 256, 256, 0, stream>>>(
        lk, lb, dw, dbm, pw, pbm, flag, w);

    xproj_kernel<<<dim3(64, 256), 256, 0, stream>>>(X, emb, flag,
                                                    w + OFF_WFX, w + OFF_BIAS,
                                                    w + OFF_XPROJ);

    lstm_persistent<<<NB, 256, 0, stream>>>((unsigned short*)(w + OFF_HH),
                                            w + OFF_FH,
                                            (const unsigned short*)(w + OFF_WB),
                                            w + OFF_XPROJ,
                                            seqlen, done);

    dense_kernel<<<32, 256, 0, stream>>>(w + OFF_FH, w + OFF_WD,
                                         w + OFF_DB, w + OFF_DEN);
    logits_kernel<<<1, 128, 0, stream>>>(w + OFF_DEN, w + OFF_WP,
                                         w + OFF_PB, flag, d_out);
}